// Round 3
// baseline (334.918 us; speedup 1.0000x reference)
//
#include <hip/hip_runtime.h>

// Problem dims (from reference setup_inputs): T=256, B=128, I=512, H=512
#define T_STEPS 256
#define B_DIM   128
#define I_DIM   512
#define H_DIM   512
#define M_DIM   (T_STEPS * B_DIM)   // 32768 rows of the flattened GEMM

// GEMM tiling. 8x16 per-thread fragment: per k-step a wave does
// 6 ds_read_b128 per 128 FMAs -> per-CU LDS demand 576 cyc vs 512 FMA cyc
// -> VALUBusy ceiling ~89% (vs 67% for the 8x8 fragment).
#define BM 128
#define BN 256
#define BK 32
#define KTILES (I_DIM / BK)

// h[m][n] = sum_k x[m][k] * W[n][k] + b[n]
// A (x) is [M][K] row-major, Bw (W) is [N][K] row-major -> both K-major.
//
// LDS layout: k-major [BK][BM|BN] floats, no pad, XOR swizzle at float4
// granularity: physical_blk = logical_blk ^ rho(k), rho(k) = (k>>2)&7.
//  - staging writes: thread stages k-rows lk..lk+3 (lk = (tid&7)*4) so
//    rho = tid&7 is thread-constant; 2-way banks across the wave (free).
//  - A reads (blocks 2ty, 2ty+1): 4 broadcast addrs/inst, distinct bank
//    groups -> conflict-free.
//  - B reads (blocks {0,16,32,48}+tx): 16 distinct addrs/inst, each bank
//    group hit twice -> 2-way (free).
// Verified round 1/2: SQ_LDS_BANK_CONFLICT == 0.
//
// REGALLOC NOTE (round-2 lesson): acc[8][16] + staging needs ~210 VGPRs.
// __launch_bounds__(256,2) capped the allocator at 128 -> 70 MB of scratch
// spill traffic (WRITE_SIZE 135MB vs 64MB output) and dur 249us. Use
// (256,1): cap 256, ~220 live regs still allows 2 blocks/CU at runtime
// (2 waves/SIMD x 220 <= 512-reg per-SIMD pool).
__global__ __launch_bounds__(256, 1) void gemm_bias_f32(
    const float* __restrict__ A,
    const float* __restrict__ Bw,
    const float* __restrict__ bias,
    float* __restrict__ C)
{
    __shared__ float As[BK * BM];   // 16 KB
    __shared__ float Bs[BK * BN];   // 32 KB

    const int tid = threadIdx.x;
    const int tx  = tid & 15;   // n direction (16 threads x 16 floats = 256)
    const int ty  = tid >> 4;   // m direction (16 threads x 8 floats = 128)
    const int m0  = blockIdx.y * BM;
    const int n0  = blockIdx.x * BN;

    float acc[8][16];
    #pragma unroll
    for (int i = 0; i < 8; i++)
        #pragma unroll
        for (int j = 0; j < 16; j++)
            acc[i][j] = 0.0f;

    // Staging mapping: thread loads 4 float4 from A (rows lrow+32p, p<4) and
    // 8 float4 from Bw (rows lrow+32p, p<8), k-cols lk..lk+3.
    const int lrow = tid >> 3;        // 0..31
    const int lk   = (tid & 7) * 4;   // 0,4,...,28
    const int q    = tid & 7;         // swizzle rho for this thread's k-rows

    const float* Aptr = A  + (size_t)(m0 + lrow) * I_DIM + lk;
    const float* Bptr = Bw + (size_t)(n0 + lrow) * I_DIM + lk;

    float4 av[4], bv[8];
    #pragma unroll
    for (int p = 0; p < 4; p++)
        av[p] = *(const float4*)(Aptr + (size_t)(p * 32) * I_DIM);
    #pragma unroll
    for (int p = 0; p < 8; p++)
        bv[p] = *(const float4*)(Bptr + (size_t)(p * 32) * I_DIM);

    for (int kt = 0; kt < KTILES; kt++) {
        __syncthreads();   // prior iteration's LDS reads complete

        #pragma unroll
        for (int p = 0; p < 4; p++) {
            const int r    = lrow + p * 32;
            const int base = (((r >> 2) ^ q) << 2) | (r & 3);
            As[(lk + 0) * BM + base] = av[p].x;
            As[(lk + 1) * BM + base] = av[p].y;
            As[(lk + 2) * BM + base] = av[p].z;
            As[(lk + 3) * BM + base] = av[p].w;
        }
        #pragma unroll
        for (int p = 0; p < 8; p++) {
            const int r    = lrow + p * 32;
            const int base = (((r >> 2) ^ q) << 2) | (r & 3);
            Bs[(lk + 0) * BN + base] = bv[p].x;
            Bs[(lk + 1) * BN + base] = bv[p].y;
            Bs[(lk + 2) * BN + base] = bv[p].z;
            Bs[(lk + 3) * BN + base] = bv[p].w;
        }

        __syncthreads();

        // Prefetch next tile into registers; latency hidden under compute.
        if (kt + 1 < KTILES) {
            const int k0 = (kt + 1) * BK;
            #pragma unroll
            for (int p = 0; p < 4; p++)
                av[p] = *(const float4*)(Aptr + (size_t)(p * 32) * I_DIM + k0);
            #pragma unroll
            for (int p = 0; p < 8; p++)
                bv[p] = *(const float4*)(Bptr + (size_t)(p * 32) * I_DIM + k0);
        }

        const float4* As4 = (const float4*)As;
        const float4* Bs4 = (const float4*)Bs;
        for (int kk = 0; kk < BK; kk += 4) {
            const int rho = (kk >> 2) & 7;
            #pragma unroll
            for (int kj = 0; kj < 4; kj++) {
                const int k = kk + kj;
                float4 a0 = As4[k * (BM / 4) + ((ty * 2)     ^ rho)];
                float4 a1 = As4[k * (BM / 4) + ((ty * 2 + 1) ^ rho)];
                float4 b0 = Bs4[k * (BN / 4) + ( tx        ^ rho)];
                float4 b1 = Bs4[k * (BN / 4) + ((16 + tx)  ^ rho)];
                float4 b2 = Bs4[k * (BN / 4) + ((32 + tx)  ^ rho)];
                float4 b3 = Bs4[k * (BN / 4) + ((48 + tx)  ^ rho)];
                float a[8]  = {a0.x, a0.y, a0.z, a0.w, a1.x, a1.y, a1.z, a1.w};
                float b[16] = {b0.x, b0.y, b0.z, b0.w, b1.x, b1.y, b1.z, b1.w,
                               b2.x, b2.y, b2.z, b2.w, b3.x, b3.y, b3.z, b3.w};
                #pragma unroll
                for (int i = 0; i < 8; i++)
                    #pragma unroll
                    for (int j = 0; j < 16; j++)
                        acc[i][j] = fmaf(a[i], b[j], acc[i][j]);
            }
        }
    }

    // Epilogue: bias + store. Column segments: n0 + 64*s + tx*4, s = 0..3.
    float4 bc[4];
    #pragma unroll
    for (int s = 0; s < 4; s++)
        bc[s] = *(const float4*)(bias + n0 + 64 * s + tx * 4);

    #pragma unroll
    for (int i = 0; i < 8; i++) {
        const int m = m0 + ty * 8 + i;
        float* cp = C + (size_t)m * H_DIM + n0 + tx * 4;
        #pragma unroll
        for (int s = 0; s < 4; s++) {
            float4 o;
            o.x = acc[i][4 * s + 0] + bc[s].x;
            o.y = acc[i][4 * s + 1] + bc[s].y;
            o.z = acc[i][4 * s + 2] + bc[s].z;
            o.w = acc[i][4 * s + 3] + bc[s].w;
            *(float4*)(cp + 64 * s) = o;
        }
    }
}

// LIF scan over T. One thread per neuron (b, j); n = B*H neurons.
// v <- v/2 + h_t ; s = (v >= 1) ; v <- s ? 0 : v
//
// Only 1024 waves exist (1 wave/SIMD) -> batch load latency is exposed once
// per 16 steps. Ping-pong prefetch: issue next 16 loads BEFORE running the
// current dependent chain. In-flight <= 32 loads + 16 stores = 48 < vmcnt
// cap 63. (Round-1 lesson: 32-deep buffers + interleaved stores exceeded
// the 63-instruction vmcnt cap -> issue stalls -> regression.)
#define SCAN_U 16
__global__ __launch_bounds__(256) void lif_scan(
    const float* __restrict__ h,
    float* __restrict__ out)
{
    const int n   = B_DIM * H_DIM;   // 65536
    const int idx = blockIdx.x * 256 + threadIdx.x;
    const float* hp = h + idx;
    float* op = out + idx;

    float bufA[SCAN_U], bufB[SCAN_U];
    float sA[SCAN_U], sB[SCAN_U];

    #pragma unroll
    for (int i = 0; i < SCAN_U; i++)
        bufA[i] = hp[(size_t)i * n];

    float v = 0.0f;
    for (int t0 = 0; t0 < T_STEPS; t0 += 2 * SCAN_U) {
        // prefetch batch B (t0+U .. t0+2U-1) before chewing on A
        #pragma unroll
        for (int i = 0; i < SCAN_U; i++)
            bufB[i] = hp[(size_t)(t0 + SCAN_U + i) * n];

        #pragma unroll
        for (int i = 0; i < SCAN_U; i++) {
            v = 0.5f * v + bufA[i];
            const bool fire = (v >= 1.0f);
            sA[i] = fire ? 1.0f : 0.0f;
            v     = fire ? 0.0f : v;
        }
        #pragma unroll
        for (int i = 0; i < SCAN_U; i++)
            op[(size_t)(t0 + i) * n] = sA[i];

        // prefetch next batch A (t0+2U ..)
        if (t0 + 2 * SCAN_U < T_STEPS) {
            #pragma unroll
            for (int i = 0; i < SCAN_U; i++)
                bufA[i] = hp[(size_t)(t0 + 2 * SCAN_U + i) * n];
        }

        #pragma unroll
        for (int i = 0; i < SCAN_U; i++) {
            v = 0.5f * v + bufB[i];
            const bool fire = (v >= 1.0f);
            sB[i] = fire ? 1.0f : 0.0f;
            v     = fire ? 0.0f : v;
        }
        #pragma unroll
        for (int i = 0; i < SCAN_U; i++)
            op[(size_t)(t0 + SCAN_U + i) * n] = sB[i];
    }
}

extern "C" void kernel_launch(void* const* d_in, const int* in_sizes, int n_in,
                              void* d_out, int out_size, void* d_ws, size_t ws_size,
                              hipStream_t stream) {
    const float* x = (const float*)d_in[0];   // (T, B, I) fp32
    const float* W = (const float*)d_in[1];   // (H, I)    fp32
    const float* b = (const float*)d_in[2];   // (H,)      fp32
    float* out = (float*)d_out;               // (T, B, H) fp32 spikes
    float* h   = (float*)d_ws;                // (T*B, H) fp32 scratch = 64 MB

    dim3 grid(H_DIM / BN, M_DIM / BM);        // (2, 256) = 512 blocks, 2/CU
    gemm_bias_f32<<<grid, 256, 0, stream>>>(x, W, b, h);

    lif_scan<<<(B_DIM * H_DIM) / 256, 256, 0, stream>>>(h, out);
}

// Round 4
// 306.899 us; speedup vs baseline: 1.0913x; 1.0913x over previous
//
#include <hip/hip_runtime.h>

// Problem dims (from reference setup_inputs): T=256, B=128, I=512, H=512
#define T_STEPS 256
#define B_DIM   128
#define I_DIM   512
#define H_DIM   512
#define M_DIM   (T_STEPS * B_DIM)   // 32768 rows of the flattened GEMM

// GEMM tiling — R1 configuration, measured 215.5 us (VGPR=60, VALUBusy 73%,
// SQ_LDS_BANK_CONFLICT=0). This is the structural ceiling of the 8x8
// fragment: per k-step a wave does 4 ds_read_b128 (~12 cyc each, m134) per
// 128 SIMD-cycles of FMA; 4 waves share one LDS unit -> demand/supply = 1.5
// -> FMA duty ceiling ~67-75%. We measure 73%.
//
// ROUND 2/3 LESSONS (do not retry as-is): the 8x16 fragment (acc=128 VGPRs)
// with register-staged prefetch is un-allocatable:
//   - (256,2) capped regs at 128 -> 70 MB scratch spill (WRITE_SIZE 135MB).
//   - (256,1) alloc chose 144 regs and SANK the prefetch loads past the
//     barrier (no spill, but pipeline destroyed; VALUBusy 51%, occ 11%).
// Next viable vehicle for the bigger fragment: __builtin_amdgcn_global_load_lds
// staging (zero staging registers) + m-major LDS + BK=16 double-buffer.
#define BM 128
#define BN 128
#define BK 32
#define KTILES (I_DIM / BK)

// h[m][n] = sum_k x[m][k] * W[n][k] + b[n]
// A (x) is [M][K] row-major, Bw (W) is [N][K] row-major -> both K-major.
//
// LDS layout: k-major [BK][128] floats, no pad, XOR swizzle at float4
// granularity: physical_blk = logical_blk ^ rho(k), rho(k) = (k>>2)&7.
//  - staging writes: thread stages k-rows lk..lk+3 (lk=(tid&7)*4) so
//    rho = tid&7 is thread-constant -> 2-way banks across the wave (free).
//  - A reads (blocks 2ty, 2ty+1): broadcast, conflict-free.
//  - B reads (blocks tx, 16+tx): 2-way (free).
// Verified: SQ_LDS_BANK_CONFLICT == 0 (rounds 1-3).
__global__ __launch_bounds__(256, 3) void gemm_bias_f32(
    const float* __restrict__ A,
    const float* __restrict__ Bw,
    const float* __restrict__ bias,
    float* __restrict__ C)
{
    __shared__ float As[BK * BM];   // 16 KB
    __shared__ float Bs[BK * BN];   // 16 KB

    const int tid = threadIdx.x;
    const int tx  = tid & 15;   // n direction (16 threads x 8 floats)
    const int ty  = tid >> 4;   // m direction (16 threads x 8 floats)
    const int m0  = blockIdx.y * BM;
    const int n0  = blockIdx.x * BN;

    float acc[8][8];
    #pragma unroll
    for (int i = 0; i < 8; i++)
        #pragma unroll
        for (int j = 0; j < 8; j++)
            acc[i][j] = 0.0f;

    // Tile-staging mapping: each thread loads 4x float4 from A and Bw.
    const int lrow = tid >> 3;        // 0..31 (row within 32-row slab)
    const int lk   = (tid & 7) * 4;   // k offset 0,4,...,28
    const int q    = tid & 7;         // swizzle rho for this thread's 4 k-rows

    const float* Aptr = A  + (size_t)(m0 + lrow) * I_DIM + lk;
    const float* Bptr = Bw + (size_t)(n0 + lrow) * I_DIM + lk;

    for (int k0 = 0; k0 < I_DIM; k0 += BK) {
        float4 av[4], bv[4];
        #pragma unroll
        for (int p = 0; p < 4; p++) {
            av[p] = *(const float4*)(Aptr + (size_t)(p * 32) * I_DIM + k0);
            bv[p] = *(const float4*)(Bptr + (size_t)(p * 32) * I_DIM + k0);
        }

        __syncthreads();   // protect prior iteration's LDS reads

        #pragma unroll
        for (int p = 0; p < 4; p++) {
            const int r    = lrow + p * 32;
            const int base = (((r >> 2) ^ q) << 2) | (r & 3);  // swizzled col
            As[(lk + 0) * BM + base] = av[p].x;
            As[(lk + 1) * BM + base] = av[p].y;
            As[(lk + 2) * BM + base] = av[p].z;
            As[(lk + 3) * BM + base] = av[p].w;
            Bs[(lk + 0) * BN + base] = bv[p].x;
            Bs[(lk + 1) * BN + base] = bv[p].y;
            Bs[(lk + 2) * BN + base] = bv[p].z;
            Bs[(lk + 3) * BN + base] = bv[p].w;
        }

        __syncthreads();

        const float4* As4 = (const float4*)As;
        const float4* Bs4 = (const float4*)Bs;
        for (int k = 0; k < BK; k++) {
            const int rho = (k >> 2) & 7;
            // a: rows m0 + ty*8 .. ty*8+7  (logical blocks 2ty, 2ty+1)
            float4 a0 = As4[k * (BM / 4) + ((ty * 2)     ^ rho)];
            float4 a1 = As4[k * (BM / 4) + ((ty * 2 + 1) ^ rho)];
            // b: cols n0 + tx*4..+3 and n0 + 64 + tx*4..+3 (blocks tx, 16+tx)
            float4 b0 = Bs4[k * (BN / 4) + (tx        ^ rho)];
            float4 b1 = Bs4[k * (BN / 4) + ((16 + tx) ^ rho)];
            float a[8] = {a0.x, a0.y, a0.z, a0.w, a1.x, a1.y, a1.z, a1.w};
            float b[8] = {b0.x, b0.y, b0.z, b0.w, b1.x, b1.y, b1.z, b1.w};
            #pragma unroll
            for (int i = 0; i < 8; i++)
                #pragma unroll
                for (int j = 0; j < 8; j++)
                    acc[i][j] = fmaf(a[i], b[j], acc[i][j]);
        }
    }

    // Epilogue: add bias, write split-column float4s
    float4 bc0 = *(const float4*)(bias + n0 + tx * 4);
    float4 bc1 = *(const float4*)(bias + n0 + 64 + tx * 4);

    #pragma unroll
    for (int i = 0; i < 8; i++) {
        const int m = m0 + ty * 8 + i;
        float4 o0, o1;
        o0.x = acc[i][0] + bc0.x;
        o0.y = acc[i][1] + bc0.y;
        o0.z = acc[i][2] + bc0.z;
        o0.w = acc[i][3] + bc0.w;
        o1.x = acc[i][4] + bc1.x;
        o1.y = acc[i][5] + bc1.y;
        o1.z = acc[i][6] + bc1.z;
        o1.w = acc[i][7] + bc1.w;
        float* cp = C + (size_t)m * H_DIM + n0;
        *(float4*)(cp + tx * 4)      = o0;
        *(float4*)(cp + 64 + tx * 4) = o1;
    }
}

// LIF scan over T. One thread per neuron (b, j); n = B*H neurons.
// v <- v/2 + h_t ; s = (v >= 1) ; v <- s ? 0 : v
//
// R3 form, measured ~67 us (vs 82 us without ping-pong, 105 us at depth 32
// with NT stores). Only 1024 waves exist (1 wave/SIMD) -> batch load latency
// is exposed once per 16 steps; ping-pong prefetch (issue next 16 loads
// BEFORE the dependent chain) hides it. In-flight <= 32 loads + 16 stores
// = 48 < vmcnt cap 63.
#define SCAN_U 16
__global__ __launch_bounds__(256) void lif_scan(
    const float* __restrict__ h,
    float* __restrict__ out)
{
    const int n   = B_DIM * H_DIM;   // 65536
    const int idx = blockIdx.x * 256 + threadIdx.x;
    const float* hp = h + idx;
    float* op = out + idx;

    float bufA[SCAN_U], bufB[SCAN_U];
    float sA[SCAN_U], sB[SCAN_U];

    #pragma unroll
    for (int i = 0; i < SCAN_U; i++)
        bufA[i] = hp[(size_t)i * n];

    float v = 0.0f;
    for (int t0 = 0; t0 < T_STEPS; t0 += 2 * SCAN_U) {
        // prefetch batch B (t0+U .. t0+2U-1) before chewing on A
        #pragma unroll
        for (int i = 0; i < SCAN_U; i++)
            bufB[i] = hp[(size_t)(t0 + SCAN_U + i) * n];

        #pragma unroll
        for (int i = 0; i < SCAN_U; i++) {
            v = 0.5f * v + bufA[i];
            const bool fire = (v >= 1.0f);
            sA[i] = fire ? 1.0f : 0.0f;
            v     = fire ? 0.0f : v;
        }
        #pragma unroll
        for (int i = 0; i < SCAN_U; i++)
            op[(size_t)(t0 + i) * n] = sA[i];

        // prefetch next batch A (t0+2U ..)
        if (t0 + 2 * SCAN_U < T_STEPS) {
            #pragma unroll
            for (int i = 0; i < SCAN_U; i++)
                bufA[i] = hp[(size_t)(t0 + 2 * SCAN_U + i) * n];
        }

        #pragma unroll
        for (int i = 0; i < SCAN_U; i++) {
            v = 0.5f * v + bufB[i];
            const bool fire = (v >= 1.0f);
            sB[i] = fire ? 1.0f : 0.0f;
            v     = fire ? 0.0f : v;
        }
        #pragma unroll
        for (int i = 0; i < SCAN_U; i++)
            op[(size_t)(t0 + SCAN_U + i) * n] = sB[i];
    }
}

extern "C" void kernel_launch(void* const* d_in, const int* in_sizes, int n_in,
                              void* d_out, int out_size, void* d_ws, size_t ws_size,
                              hipStream_t stream) {
    const float* x = (const float*)d_in[0];   // (T, B, I) fp32
    const float* W = (const float*)d_in[1];   // (H, I)    fp32
    const float* b = (const float*)d_in[2];   // (H,)      fp32
    float* out = (float*)d_out;               // (T, B, H) fp32 spikes
    float* h   = (float*)d_ws;                // (T*B, H) fp32 scratch = 64 MB

    dim3 grid(H_DIM / BN, M_DIM / BM);        // (4, 256) = 1024 blocks
    gemm_bias_f32<<<grid, 256, 0, stream>>>(x, W, b, h);

    lif_scan<<<(B_DIM * H_DIM) / 256, 256, 0, stream>>>(h, out);
}